// Round 11
// baseline (307.016 us; speedup 1.0000x reference)
//
#include <hip/hip_runtime.h>
#include <hip/hip_bf16.h>

typedef __bf16 bf16x8 __attribute__((ext_vector_type(8)));
typedef float  f32x4  __attribute__((ext_vector_type(4)));

#define SIZE_  131072
#define DIM_   128
#define BATCH_ 1024
#define KNN_   16

#define BM 32
#define BN 128
#define MT (BATCH_ / BM)          // 32
#define NT (SIZE_ / BN)           // 1024
#define NWG (MT * NT)             // 32768

// ---------------- prep: emb -> bf16 + e_sq ----------------
__global__ __launch_bounds__(256) void prep_emb(const float* __restrict__ emb,
                                                __bf16* __restrict__ emb16,
                                                float* __restrict__ e_sq) {
    int wid  = (blockIdx.x * 256 + threadIdx.x) >> 6;   // row 0..1023
    int lane = threadIdx.x & 63;
    float2 v = *reinterpret_cast<const float2*>(emb + (size_t)wid * DIM_ + lane * 2);
    float s = v.x * v.x + v.y * v.y;
    #pragma unroll
    for (int off = 32; off; off >>= 1) s += __shfl_xor(s, off);
    union { __bf16 h[2]; unsigned int u; } pk;
    pk.h[0] = (__bf16)v.x; pk.h[1] = (__bf16)v.y;
    *reinterpret_cast<unsigned int*>(emb16 + (size_t)wid * DIM_ + lane * 2) = pk.u;
    if (lane == 0) e_sq[wid] = s;
}

// ---------------- GEMM + fused {bank copy, b_sq, distance, knn} ----------------
// R7 structure, tile reshaped to 32x128: output runs 512B/row, single-round
// staging, 3 barriers, 33KB LDS (lB 32KB overlaps ftile 32KB), nt writeback.
__global__ __launch_bounds__(256) void gemm_dist(const float* __restrict__ bank,
                                                 const __bf16* __restrict__ emb16,
                                                 const float* __restrict__ e_sq,
                                                 const float* __restrict__ emb,
                                                 const int* __restrict__ idxs,
                                                 float* __restrict__ out_dist,
                                                 float* __restrict__ out_dots,
                                                 float* __restrict__ out_bank,
                                                 float* __restrict__ out_knn) {
    __shared__ alignas(16) char smem[33280];
    char*  lBc   = smem;                       // [0, 32768) bf16 B-tile, 128 rows x 256B (swizzled)
    char*  ftile = smem;                       // [0, 32768) f32 out-tiles: dist | dots (32 x 512B each)
    float* bsq   = (float*)(smem + 32768);     // 128 f32

    int bid  = blockIdx.x;
    int tid  = threadIdx.x;
    int wv   = tid >> 6;
    int lane = tid & 63;

    // ---- folded knn: first 4096 blocks, one (b,k) pair per wave ----
    if (bid < (BATCH_ * KNN_) / 4) {
        int wid = bid * 4 + wv;
        int b   = wid >> 4;
        int idx = idxs[wid];
        float2 br = *reinterpret_cast<const float2*>(bank + (size_t)idx * DIM_ + lane * 2);
        float2 er = *reinterpret_cast<const float2*>(emb + (size_t)b * DIM_ + lane * 2);
        float s = br.x * er.x + br.y * er.y;
        #pragma unroll
        for (int off = 32; off; off >>= 1) s += __shfl_xor(s, off);
        if (lane == 0) out_knn[wid] = s;
    }

    // XCD-chunked swizzle, mt fastest: 32 m-tiles share one B-panel on one XCD
    int logical = (bid & 7) * (NWG / 8) + (bid >> 3);
    int mt = logical & (MT - 1);
    int nt = logical >> 5;
    int m0 = mt * BM;
    int n0 = nt * BN;

    int lr   = lane & 15;       // fragment row/col
    int rgrp = lane >> 4;
    int lkb  = rgrp * 8;        // k sub-offset
    int wm   = wv >> 1;         // m-half 0..1
    int wn   = wv & 1;          // n-half 0..1

    // ---- A fragments: 16 rows x K=128 per wave, registers (L2-hot emb16) ----
    bf16x8 af[4];
    {
        const __bf16* abase = emb16 + (size_t)(m0 + wm * 16 + lr) * DIM_ + lkb;
        #pragma unroll
        for (int ks = 0; ks < 4; ++ks)
            af[ks] = *reinterpret_cast<const bf16x8*>(abase + ks * 32);
    }

    // ---- stage B: read f32 bank rows once -> bf16 LDS + b_sq (+ copy if mt==0) ----
    #pragma unroll
    for (int i = 0; i < 8; ++i) {
        int p   = i * 256 + tid;                   // 0..2047, 8 f32 each
        int row = p >> 4;                          // 128 rows, 16 chunks each
        int k0  = (p & 15) * 8;
        size_t gb = (size_t)(n0 + row) * DIM_ + k0;
        const f32x4* s4 = reinterpret_cast<const f32x4*>(bank + gb);
        f32x4 a = s4[0], b = s4[1];
        if (mt == 0) {
            __builtin_nontemporal_store(a, reinterpret_cast<f32x4*>(out_bank + gb));
            __builtin_nontemporal_store(b, reinterpret_cast<f32x4*>(out_bank + gb + 4));
        }
        float s = a.x * a.x + a.y * a.y + a.z * a.z + a.w * a.w
                + b.x * b.x + b.y * b.y + b.z * b.z + b.w * b.w;
        #pragma unroll
        for (int off = 8; off; off >>= 1) s += __shfl_xor(s, off);  // 16-lane row group
        if ((p & 15) == 0) bsq[row] = s;
        union { __bf16 h[8]; int4 v; } pk;
        pk.h[0] = (__bf16)a.x; pk.h[1] = (__bf16)a.y; pk.h[2] = (__bf16)a.z; pk.h[3] = (__bf16)a.w;
        pk.h[4] = (__bf16)b.x; pk.h[5] = (__bf16)b.y; pk.h[6] = (__bf16)b.z; pk.h[7] = (__bf16)b.w;
        int o  = (row << 8) + k0 * 2;
        int so = o ^ ((row & 7) << 4);
        *reinterpret_cast<int4*>(lBc + so) = pk.v;
    }
    __syncthreads();                                         // barrier 1

    // ---- K-loop: 16 MFMA per wave ----
    f32x4 acc[4] = {};
    #pragma unroll
    for (int ks = 0; ks < 4; ++ks) {
        int kk = ks * 32 + lkb;
        bf16x8 bf[4];
        #pragma unroll
        for (int nc = 0; nc < 4; ++nc) {
            int row = wn * 64 + nc * 16 + lr;
            int o   = (row << 8) + kk * 2;
            bf[nc]  = *reinterpret_cast<const bf16x8*>(lBc + (o ^ ((row & 7) << 4)));
        }
        #pragma unroll
        for (int nc = 0; nc < 4; ++nc)
            acc[nc] = __builtin_amdgcn_mfma_f32_16x16x32_bf16(af[ks], bf[nc], acc[nc], 0, 0, 0);
    }

    // ---- epilogue: scalars, then one scatter + one burst writeback ----
    float bs[4];
    #pragma unroll
    for (int nc = 0; nc < 4; ++nc) bs[nc] = bsq[wn * 64 + nc * 16 + lr];
    float es[4];
    #pragma unroll
    for (int j = 0; j < 4; ++j) es[j] = e_sq[m0 + wm * 16 + rgrp * 4 + j];

    __syncthreads();                                         // barrier 2 (lB free)

    #pragma unroll
    for (int j = 0; j < 4; ++j) {
        int row = wm * 16 + rgrp * 4 + j;                    // local row 0..31
        int sw  = (row & 7) << 4;
        #pragma unroll
        for (int nc = 0; nc < 4; ++nc) {
            float d   = acc[nc][j];
            float arg = es[j] + bs[nc] - 2.0f * d;
            int o = (row << 9) + (wn * 64 + nc * 16 + lr) * 4;
            *reinterpret_cast<float*>(ftile + (o ^ sw))         = sqrtf(fmaxf(arg, 0.0f));
            *reinterpret_cast<float*>(ftile + 16384 + (o ^ sw)) = d;
        }
    }
    __syncthreads();                                         // barrier 3

    // burst writeback: 8 x 16B per thread, both outputs, nontemporal; 512B/row runs
    #pragma unroll
    for (int i = 0; i < 8; ++i) {
        int p    = i * 256 + tid;          // 0..2047 16B-chunks over 32KB
        int half = p >> 10;                // 0 = dist, 1 = dots
        int pr   = p & 1023;
        int row  = pr >> 5;                // 0..31
        int c4   = pr & 31;                // 32 x 16B chunks per row
        int o    = (row << 9) + c4 * 16;
        f32x4 v = *reinterpret_cast<const f32x4*>(ftile + half * 16384 + (o ^ ((row & 7) << 4)));
        size_t ga = (size_t)(m0 + row) * SIZE_ + n0 + c4 * 4;
        float* outp = half ? out_dots : out_dist;
        __builtin_nontemporal_store(v, reinterpret_cast<f32x4*>(outp + ga));
    }
}

// ---------------- scatter rows (last occurrence wins) ----------------
__global__ __launch_bounds__(128) void scatter_rows(const float* __restrict__ dmem,
                                                    const int* __restrict__ upd,
                                                    float* __restrict__ newbank) {
    int i = blockIdx.x;
    int idx = upd[i];
    __shared__ int dup;
    if (threadIdx.x == 0) dup = 0;
    __syncthreads();
    for (int j = i + 1 + threadIdx.x; j < BATCH_; j += 128)
        if (upd[j] == idx) dup = 1;
    __syncthreads();
    if (dup) return;
    newbank[(size_t)idx * DIM_ + threadIdx.x] = dmem[(size_t)i * DIM_ + threadIdx.x];
}

extern "C" void kernel_launch(void* const* d_in, const int* in_sizes, int n_in,
                              void* d_out, int out_size, void* d_ws, size_t ws_size,
                              hipStream_t stream) {
    const float* emb  = (const float*)d_in[0];
    const float* dmem = (const float*)d_in[1];
    const float* bank = (const float*)d_in[2];
    const int*   idxs = (const int*)d_in[3];
    const int*   upd  = (const int*)d_in[4];

    float* out       = (float*)d_out;
    float* out_dist  = out;
    float* out_dots  = out + (size_t)BATCH_ * SIZE_;
    float* out_knn   = out + (size_t)2 * BATCH_ * SIZE_;
    float* out_bank  = out_knn + (size_t)BATCH_ * KNN_;

    char*   ws    = (char*)d_ws;
    float*  e_sq  = (float*)ws;                        // 1024 f32 = 4 KB
    __bf16* emb16 = (__bf16*)(ws + 4096);              // 1024*128 bf16 = 256 KB

    prep_emb <<<BATCH_ / 4, 256, 0, stream>>>(emb, emb16, e_sq);
    gemm_dist<<<NWG,        256, 0, stream>>>(bank, emb16, e_sq, emb, idxs,
                                              out_dist, out_dots, out_bank, out_knn);
    scatter_rows<<<BATCH_,  128, 0, stream>>>(dmem, upd, out_bank);
}

// Round 12
// 259.663 us; speedup vs baseline: 1.1824x; 1.1824x over previous
//
#include <hip/hip_runtime.h>
#include <hip/hip_bf16.h>

typedef __bf16 bf16x8 __attribute__((ext_vector_type(8)));
typedef float  f32x4  __attribute__((ext_vector_type(4)));

#define SIZE_  131072
#define DIM_   128
#define BATCH_ 1024
#define KNN_   16

#define BM 64
#define BN 64
#define MT (BATCH_ / BM)          // 16
#define NT (SIZE_ / BN)           // 2048
#define NWG (MT * NT)             // 32768

// ---------------- prep: emb -> bf16 + e_sq ----------------
__global__ __launch_bounds__(256) void prep_emb(const float* __restrict__ emb,
                                                __bf16* __restrict__ emb16,
                                                float* __restrict__ e_sq) {
    int wid  = (blockIdx.x * 256 + threadIdx.x) >> 6;   // row 0..1023
    int lane = threadIdx.x & 63;
    float2 v = *reinterpret_cast<const float2*>(emb + (size_t)wid * DIM_ + lane * 2);
    float s = v.x * v.x + v.y * v.y;
    #pragma unroll
    for (int off = 32; off; off >>= 1) s += __shfl_xor(s, off);
    union { __bf16 h[2]; unsigned int u; } pk;
    pk.h[0] = (__bf16)v.x; pk.h[1] = (__bf16)v.y;
    *reinterpret_cast<unsigned int*>(emb16 + (size_t)wid * DIM_ + lane * 2) = pk.u;
    if (lane == 0) e_sq[wid] = s;
}

// ---------------- GEMM + fused {bank copy, b_sq, distance, knn} ----------------
// 64x64 tile, A in registers, B in 16KB swizzled LDS; unified 32KB ftile
// (dist+dots) overlapping lB -> 33KB LDS; 3 barriers; nt stores.
// Bank leaves HBM exactly once (mt==0 block emits new_bank copy).
// Blocks 0..4095 additionally compute one knn wave-dot each before staging.
__global__ __launch_bounds__(256) void gemm_dist(const float* __restrict__ bank,
                                                 const __bf16* __restrict__ emb16,
                                                 const float* __restrict__ e_sq,
                                                 const float* __restrict__ emb,
                                                 const int* __restrict__ idxs,
                                                 float* __restrict__ out_dist,
                                                 float* __restrict__ out_dots,
                                                 float* __restrict__ out_bank,
                                                 float* __restrict__ out_knn) {
    __shared__ alignas(16) char smem[33024];
    char*  lBc   = smem;                       // [0, 16384) bf16 B-tile (swizzled)
    char*  ftile = smem;                       // [0, 32768) f32 out-tiles: dist | dots
    float* bsq   = (float*)(smem + 32768);     // [32768, 33024)

    int bid  = blockIdx.x;
    int tid  = threadIdx.x;
    int wv   = tid >> 6;
    int lane = tid & 63;

    // ---- folded knn: first 4096 blocks, one (b,k) pair per wave ----
    if (bid < (BATCH_ * KNN_) / 4) {
        int wid = bid * 4 + wv;
        int b   = wid >> 4;
        int idx = idxs[wid];
        float2 br = *reinterpret_cast<const float2*>(bank + (size_t)idx * DIM_ + lane * 2);
        float2 er = *reinterpret_cast<const float2*>(emb + (size_t)b * DIM_ + lane * 2);
        float s = br.x * er.x + br.y * er.y;
        #pragma unroll
        for (int off = 32; off; off >>= 1) s += __shfl_xor(s, off);
        if (lane == 0) out_knn[wid] = s;
    }

    // XCD-chunked swizzle, mt fastest: 16 m-tiles share one B-panel on one XCD
    int logical = (bid & 7) * (NWG / 8) + (bid >> 3);
    int mt = logical & (MT - 1);
    int nt = logical >> 4;
    int m0 = mt * BM;
    int n0 = nt * BN;

    int lr   = lane & 15;       // fragment row/col
    int rgrp = lane >> 4;
    int lkb  = rgrp * 8;        // k sub-offset

    // ---- A fragments: 16 rows x K=128 per wave, registers (L2-hot emb16) ----
    bf16x8 af[4];
    {
        const __bf16* abase = emb16 + (size_t)(m0 + wv * 16 + lr) * DIM_ + lkb;
        #pragma unroll
        for (int ks = 0; ks < 4; ++ks)
            af[ks] = *reinterpret_cast<const bf16x8*>(abase + ks * 32);
    }

    // ---- stage B: read f32 bank rows once -> bf16 LDS + b_sq (+ copy if mt==0) ----
    #pragma unroll
    for (int i = 0; i < 4; ++i) {
        int p   = i * 256 + tid;                   // 0..1023, 8 f32 each
        int row = p >> 4;                          // 64 rows, 16 chunks each
        int k0  = (p & 15) * 8;
        size_t gb = (size_t)(n0 + row) * DIM_ + k0;
        const f32x4* s4 = reinterpret_cast<const f32x4*>(bank + gb);
        f32x4 a = s4[0], b = s4[1];
        if (mt == 0) {
            __builtin_nontemporal_store(a, reinterpret_cast<f32x4*>(out_bank + gb));
            __builtin_nontemporal_store(b, reinterpret_cast<f32x4*>(out_bank + gb + 4));
        }
        float s = a.x * a.x + a.y * a.y + a.z * a.z + a.w * a.w
                + b.x * b.x + b.y * b.y + b.z * b.z + b.w * b.w;
        #pragma unroll
        for (int off = 8; off; off >>= 1) s += __shfl_xor(s, off);  // 16-lane row group
        if ((p & 15) == 0) bsq[row] = s;
        union { __bf16 h[8]; int4 v; } pk;
        pk.h[0] = (__bf16)a.x; pk.h[1] = (__bf16)a.y; pk.h[2] = (__bf16)a.z; pk.h[3] = (__bf16)a.w;
        pk.h[4] = (__bf16)b.x; pk.h[5] = (__bf16)b.y; pk.h[6] = (__bf16)b.z; pk.h[7] = (__bf16)b.w;
        int o  = (row << 8) + k0 * 2;
        int so = o ^ ((row & 7) << 4);
        *reinterpret_cast<int4*>(lBc + so) = pk.v;
    }
    __syncthreads();                                         // barrier 1

    // ---- K-loop: 16 MFMA per wave ----
    f32x4 acc[4] = {};
    #pragma unroll
    for (int ks = 0; ks < 4; ++ks) {
        int kk = ks * 32 + lkb;
        bf16x8 bf[4];
        #pragma unroll
        for (int nc = 0; nc < 4; ++nc) {
            int row = nc * 16 + lr;
            int o   = (row << 8) + kk * 2;
            bf[nc]  = *reinterpret_cast<const bf16x8*>(lBc + (o ^ ((row & 7) << 4)));
        }
        #pragma unroll
        for (int nc = 0; nc < 4; ++nc)
            acc[nc] = __builtin_amdgcn_mfma_f32_16x16x32_bf16(af[ks], bf[nc], acc[nc], 0, 0, 0);
    }

    // ---- epilogue: scalars, then one scatter + one burst writeback ----
    float bs[4];
    #pragma unroll
    for (int nc = 0; nc < 4; ++nc) bs[nc] = bsq[nc * 16 + lr];
    float es[4];
    #pragma unroll
    for (int j = 0; j < 4; ++j) es[j] = e_sq[m0 + wv * 16 + rgrp * 4 + j];

    __syncthreads();                                         // barrier 2 (lB free)

    #pragma unroll
    for (int j = 0; j < 4; ++j) {
        int row = wv * 16 + rgrp * 4 + j;                    // local row 0..63
        int sw  = (row & 7) << 4;
        #pragma unroll
        for (int nc = 0; nc < 4; ++nc) {
            float d   = acc[nc][j];
            float arg = es[j] + bs[nc] - 2.0f * d;
            int o = (row << 8) + (nc * 16 + lr) * 4;
            *reinterpret_cast<float*>(ftile + (o ^ sw))         = sqrtf(fmaxf(arg, 0.0f));
            *reinterpret_cast<float*>(ftile + 16384 + (o ^ sw)) = d;
        }
    }
    __syncthreads();                                         // barrier 3

    // burst writeback: 8 x 16B per thread, both outputs, nontemporal
    #pragma unroll
    for (int i = 0; i < 8; ++i) {
        int p    = i * 256 + tid;          // 0..2047 16B-chunks over 32KB
        int half = p >> 10;                // 0 = dist, 1 = dots
        int pr   = p & 1023;
        int row  = pr >> 4;
        int c4   = pr & 15;
        int o    = (row << 8) + c4 * 16;
        f32x4 v = *reinterpret_cast<const f32x4*>(ftile + half * 16384 + (o ^ ((row & 7) << 4)));
        size_t ga = (size_t)(m0 + row) * SIZE_ + n0 + c4 * 4;
        float* outp = half ? out_dots : out_dist;
        __builtin_nontemporal_store(v, reinterpret_cast<f32x4*>(outp + ga));
    }
}

// ---------------- scatter rows (last occurrence wins) ----------------
__global__ __launch_bounds__(128) void scatter_rows(const float* __restrict__ dmem,
                                                    const int* __restrict__ upd,
                                                    float* __restrict__ newbank) {
    int i = blockIdx.x;
    int idx = upd[i];
    __shared__ int dup;
    if (threadIdx.x == 0) dup = 0;
    __syncthreads();
    for (int j = i + 1 + threadIdx.x; j < BATCH_; j += 128)
        if (upd[j] == idx) dup = 1;
    __syncthreads();
    if (dup) return;
    newbank[(size_t)idx * DIM_ + threadIdx.x] = dmem[(size_t)i * DIM_ + threadIdx.x];
}

extern "C" void kernel_launch(void* const* d_in, const int* in_sizes, int n_in,
                              void* d_out, int out_size, void* d_ws, size_t ws_size,
                              hipStream_t stream) {
    const float* emb  = (const float*)d_in[0];
    const float* dmem = (const float*)d_in[1];
    const float* bank = (const float*)d_in[2];
    const int*   idxs = (const int*)d_in[3];
    const int*   upd  = (const int*)d_in[4];

    float* out       = (float*)d_out;
    float* out_dist  = out;
    float* out_dots  = out + (size_t)BATCH_ * SIZE_;
    float* out_knn   = out + (size_t)2 * BATCH_ * SIZE_;
    float* out_bank  = out_knn + (size_t)BATCH_ * KNN_;

    char*   ws    = (char*)d_ws;
    float*  e_sq  = (float*)ws;                        // 1024 f32 = 4 KB
    __bf16* emb16 = (__bf16*)(ws + 4096);              // 1024*128 bf16 = 256 KB

    prep_emb <<<BATCH_ / 4, 256, 0, stream>>>(emb, emb16, e_sq);
    gemm_dist<<<NWG,        256, 0, stream>>>(bank, emb16, e_sq, emb, idxs,
                                              out_dist, out_dots, out_bank, out_knn);
    scatter_rows<<<BATCH_,  128, 0, stream>>>(dmem, upd, out_bank);
}